// Round 1
// baseline (189.085 us; speedup 1.0000x reference)
//
#include <hip/hip_runtime.h>

#define C2LOG2E 2.8853900817779268f   // 2*log2(e): exp(2x) = exp2(C2LOG2E*x)
#define LOG2E   1.4426950408889634f

// ---------------- Kernel 1: fused projections, pre-scaled by 2*log2(e) -----
// rows 0..1023   -> qc[r] = C * (queries[r] @ Wq)
// rows 1024..5119-> kc[r-1024] = C * (keys[r-1024] @ Wk)
__global__ __launch_bounds__(256) void proj_kernel(
    const float* __restrict__ q_in, const float* __restrict__ k_in,
    const float* __restrict__ Wq, const float* __restrict__ Wk,
    float* __restrict__ qc, float* __restrict__ kc)
{
    __shared__ float in_s[4][128];
    int tid = threadIdx.x;
    int r0 = blockIdx.x * 4;            // 4 rows per block, grid=1280
    int rl = tid >> 7;                  // 0..1
    int d  = tid & 127;
    bool is_q = (r0 < 1024);
#pragma unroll
    for (int j = 0; j < 2; ++j) {
        int r = r0 + 2*j + rl;
        const float* src = is_q ? (q_in + (size_t)r*128)
                                : (k_in + (size_t)(r-1024)*128);
        in_s[2*j+rl][d] = src[d];
    }
    __syncthreads();
    const float* W = is_q ? Wq : Wk;
    float a0 = 0.f, a1 = 0.f;
    int h = d;
    int rr = rl;                        // this thread: rows rr and rr+2
#pragma unroll 4
    for (int dd = 0; dd < 128; ++dd) {
        float w = W[dd*128 + h];        // coalesced across lanes, L1/L2 hot
        a0 = fmaf(in_s[rr][dd],   w, a0);
        a1 = fmaf(in_s[rr+2][dd], w, a1);
    }
    int ra = r0 + rr, rb = r0 + rr + 2;
    float* da = is_q ? (qc + (size_t)ra*128) : (kc + (size_t)(ra-1024)*128);
    float* db = is_q ? (qc + (size_t)rb*128) : (kc + (size_t)(rb-1024)*128);
    da[h] = a0 * C2LOG2E;
    db[h] = a1 * C2LOG2E;
}

// ---------------- Kernel 2: fused scores + masked softmax + PV -------------
// grid = (128 q-tiles, 4 batches), 256 threads, Q_TILE=2.
// score'(q,kv) = -2 * sum_h wv[h] / (exp2(qc+kc)+1)   (constant Sum(wv) dropped;
// softmax is shift-invariant per row, masked slots get -1e6 like the reference)
__global__ __launch_bounds__(256, 3) void attn_kernel(
    const float* __restrict__ qc, const float* __restrict__ kc,
    const float* __restrict__ values, const int* __restrict__ valid_lens,
    const float* __restrict__ wv, float* __restrict__ out)
{
    __shared__ float  k_s[64*128];      // [h_local][kv] transposed; reused as po[4][2][256]
    __shared__ float2 qw_s[2][128];     // (qc_scaled, -2*wv)
    __shared__ float  e_s[2][1024];     // unnormalized exp-scores
    __shared__ float  red4[4];
    __shared__ float  red4b[4];

    int tid = threadIdx.x;
    int b   = blockIdx.y;
    int q0  = blockIdx.x * 2;
    int q   = tid >> 7;                 // wave-uniform (waves 0,1 -> q0; 2,3 -> q1)
    int kvl = tid & 127;
    int vl  = valid_lens[b];

    {   // preamble: (q-projection, -2*wv) pairs
        int hh = tid & 127, qq = tid >> 7;
        qw_s[qq][hh] = make_float2(qc[((size_t)(b*256 + q0 + qq))*128 + hh],
                                   -2.0f * wv[hh]);
    }

    float sc[8];
    for (int c = 0; c < 8; ++c) {       // kv chunks of 128
        float acc = 0.f;
#pragma unroll
        for (int hc = 0; hc < 2; ++hc) {        // h halves of 64 (32KB LDS tile)
            __syncthreads();                    // guard prior readers
            {   // stage kc[b, c*128 + rl, hc*64 .. +64) transposed into k_s
                int rl   = tid & 127;
                int hoff = (tid >> 7) * 32;
                const float4* src = (const float4*)(kc
                    + ((size_t)(b*1024 + c*128 + rl))*128 + hc*64 + hoff);
#pragma unroll
                for (int i = 0; i < 8; ++i) {
                    float4 kk = src[i];
                    int hl = hoff + 4*i;
                    k_s[(hl+0)*128 + rl] = kk.x;   // lane-consecutive -> no conflicts
                    k_s[(hl+1)*128 + rl] = kk.y;
                    k_s[(hl+2)*128 + rl] = kk.z;
                    k_s[(hl+3)*128 + rl] = kk.w;
                }
            }
            __syncthreads();
            const float2* qw = &qw_s[q][hc*64];
#pragma unroll 8
            for (int hl = 0; hl < 64; ++hl) {
                float  kh = k_s[hl*128 + kvl];     // conflict-free b32
                float2 w2 = qw[hl];                // wave-uniform broadcast
                float  e  = __builtin_amdgcn_exp2f(w2.x + kh);   // exp(2x)
                float  r  = __builtin_amdgcn_rcpf(e + 1.0f);
                acc = fmaf(w2.y, r, acc);          // += (-2*wv)/(e+1)
            }
        }
        int kv = c*128 + kvl;
        sc[c] = (kv < vl) ? acc : -1e6f;
    }

    // ---- masked softmax over KV (two-level: shuffle + LDS) ----
    float m = sc[0];
#pragma unroll
    for (int i = 1; i < 8; ++i) m = fmaxf(m, sc[i]);
#pragma unroll
    for (int off = 32; off; off >>= 1) m = fmaxf(m, __shfl_xor(m, off));
    int w = tid >> 6;
    if ((tid & 63) == 0) red4[w] = m;
    __syncthreads();                     // also guards last k_s reads before reuse
    m = fmaxf(red4[2*q], red4[2*q+1]);

    float ls = 0.f;
#pragma unroll
    for (int i = 0; i < 8; ++i) {
        float e = __builtin_amdgcn_exp2f((sc[i] - m) * LOG2E);
        e_s[q][i*128 + kvl] = e;
        ls += e;
    }
#pragma unroll
    for (int off = 32; off; off >>= 1) ls += __shfl_xor(ls, off);
    if ((tid & 63) == 0) red4b[w] = ls;
    __syncthreads();
    float inv = 1.0f / (red4b[2*q] + red4b[2*q+1]);

    // ---- PV: wave w handles kv = w,w+4,...; lane owns 4 consecutive v ----
    int lane = tid & 63;
    float4 a0 = {0,0,0,0}, a1 = {0,0,0,0};
    const float4* V4 = (const float4*)values + (size_t)b*1024*64;
    for (int kv = w; kv < 1024; kv += 4) {
        float4 vv = V4[(size_t)kv*64 + lane];      // coalesced 1KB/row
        float e0 = e_s[0][kv];                     // wave-uniform broadcast
        float e1 = e_s[1][kv];
        a0.x = fmaf(e0, vv.x, a0.x); a0.y = fmaf(e0, vv.y, a0.y);
        a0.z = fmaf(e0, vv.z, a0.z); a0.w = fmaf(e0, vv.w, a0.w);
        a1.x = fmaf(e1, vv.x, a1.x); a1.y = fmaf(e1, vv.y, a1.y);
        a1.z = fmaf(e1, vv.z, a1.z); a1.w = fmaf(e1, vv.w, a1.w);
    }
    float4* po4 = (float4*)k_s;          // overlay: po[w][q][256]
    po4[w*128 + lane]      = a0;         // q=0 partial
    po4[w*128 + 64 + lane] = a1;         // q=1 partial
    __syncthreads();

    int v2 = (tid & 127) * 2;
    float rx = 0.f, ry = 0.f;
#pragma unroll
    for (int ww = 0; ww < 4; ++ww) {
        float2 p = *(const float2*)&k_s[ww*512 + q*256 + v2];
        rx += p.x; ry += p.y;
    }
    float2 o = make_float2(rx * inv, ry * inv);
    ((float2*)out)[((size_t)(b*256 + q0 + q))*128 + (tid & 127)] = o;
}

extern "C" void kernel_launch(void* const* d_in, const int* in_sizes, int n_in,
                              void* d_out, int out_size, void* d_ws, size_t ws_size,
                              hipStream_t stream)
{
    const float* queries = (const float*)d_in[0];   // [4,256,128]
    const float* keys    = (const float*)d_in[1];   // [4,1024,128]
    const float* values  = (const float*)d_in[2];   // [4,1024,256]
    const int*   vlens   = (const int*)d_in[3];     // [4]
    const float* Wq      = (const float*)d_in[4];   // [128,128]
    const float* Wk      = (const float*)d_in[5];   // [128,128]
    const float* wv      = (const float*)d_in[6];   // [128]
    float* out = (float*)d_out;                     // [4,256,256]

    float* qc = (float*)d_ws;                       // 4*256*128 floats
    float* kc = qc + 4*256*128;                     // 4*1024*128 floats (2.62MB total)

    proj_kernel<<<1280, 256, 0, stream>>>(queries, keys, Wq, Wk, qc, kc);
    attn_kernel<<<dim3(128, 4), 256, 0, stream>>>(qc, kc, values, vlens, wv, out);
}

// Round 2
// 100.828 us; speedup vs baseline: 1.8753x; 1.8753x over previous
//
#include <hip/hip_runtime.h>

#define C2LOG2E 2.8853900817779268f   // 2*log2(e): exp(2x) = exp2(C2LOG2E*x)
#define LOG2E   1.4426950408889634f

__device__ __forceinline__ float sig2(float x) {   // 1/(exp2(x)+1)
    return __builtin_amdgcn_rcpf(__builtin_amdgcn_exp2f(x) + 1.0f);
}

// ---------------- Kernel 1: fused projections, pre-scaled by 2*log2(e) -----
// blocks 0..255   : qc[b,q,h] row-major (rows 0..1023 = b*256+q)
// blocks 256..1279: kct tiled-transposed: kct[b][kv>>6][h][kv&63]
__global__ __launch_bounds__(256) void proj_kernel(
    const float* __restrict__ q_in, const float* __restrict__ k_in,
    const float* __restrict__ Wq, const float* __restrict__ Wk,
    float* __restrict__ qc, float* __restrict__ kct)
{
    __shared__ __align__(16) float in_s[4][128];
    __shared__ float ts[128][4];
    int tid = threadIdx.x;
    int r0 = blockIdx.x * 4;            // 4 rows per block, grid=1280
    int rl = tid >> 7;                  // 0..1
    int d  = tid & 127;                 // h index
    bool is_q = (r0 < 1024);
#pragma unroll
    for (int j = 0; j < 2; ++j) {
        int r = r0 + 2*j + rl;
        const float* src = is_q ? (q_in + (size_t)r*128)
                                : (k_in + (size_t)(r-1024)*128);
        in_s[2*j+rl][d] = src[d];
    }
    __syncthreads();
    const float* W = is_q ? Wq : Wk;
    const float4* x0p = (const float4*)in_s[rl];
    const float4* x1p = (const float4*)in_s[rl+2];
    float4 c0 = {0,0,0,0}, c1 = {0,0,0,0};
#pragma unroll 4
    for (int d4 = 0; d4 < 32; ++d4) {
        float4 x0 = x0p[d4], x1 = x1p[d4];
        float w0 = W[(4*d4+0)*128 + d];
        float w1 = W[(4*d4+1)*128 + d];
        float w2 = W[(4*d4+2)*128 + d];
        float w3 = W[(4*d4+3)*128 + d];
        c0.x = fmaf(x0.x, w0, c0.x); c0.y = fmaf(x0.y, w1, c0.y);
        c0.z = fmaf(x0.z, w2, c0.z); c0.w = fmaf(x0.w, w3, c0.w);
        c1.x = fmaf(x1.x, w0, c1.x); c1.y = fmaf(x1.y, w1, c1.y);
        c1.z = fmaf(x1.z, w2, c1.z); c1.w = fmaf(x1.w, w3, c1.w);
    }
    float a0 = ((c0.x+c0.y)+(c0.z+c0.w)) * C2LOG2E;   // row rl
    float a1 = ((c1.x+c1.y)+(c1.z+c1.w)) * C2LOG2E;   // row rl+2

    if (is_q) {
        qc[(size_t)(r0+rl)*128 + d]   = a0;
        qc[(size_t)(r0+rl+2)*128 + d] = a1;
    } else {
        ts[d][rl]   = a0;               // micro-transpose 4kv x 128h
        ts[d][rl+2] = a1;
        __syncthreads();
        if (tid < 128) {
            int kvg = r0 - 1024;        // global k row base (mult of 4)
            int bb  = kvg >> 10;
            int kvb = kvg & 1023;
            int c   = kvb >> 6;         // 64-kv chunk
            int i   = kvb & 63;         // offset in chunk (mult of 4)
            float4 t = *(const float4*)&ts[tid][0];
            *(float4*)&kct[(((size_t)(bb*16 + c))*128 + tid)*64 + i] = t;
        }
    }
}

// ---------------- Kernel 2: fused scores + masked softmax + PV -------------
// grid (128 q-tiles, 4 b), 512 threads. Thread: 2 queries x kv {kvl, kvl+512}.
// score'(q,kv) = -2 * sum_h wv[h]/(exp2(qc+kc)+1)  (const Sum(wv) cancels in softmax)
__global__ __launch_bounds__(512, 4) void attn_kernel(
    const float* __restrict__ qc, const float* __restrict__ kct,
    const float* __restrict__ values, const int* __restrict__ valid_lens,
    const float* __restrict__ wv, float* __restrict__ out)
{
    __shared__ float2 e2_s[1024];       // (e_q0, e_q1) per kv
    __shared__ float4 po[8][2][64];     // PV wave partials
    __shared__ float  red_m[8][2], red_s[8][2];

    int tid  = threadIdx.x;
    int b    = blockIdx.y;
    int q0   = blockIdx.x * 2;
    int kvl  = tid & 511;               // kv lane; owns kvl and kvl+512
    int w    = tid >> 6;                // wave 0..7
    int lane = tid & 63;
    int vl   = valid_lens[b];

    // ---- scores: direct global reads of tiled kct (L2-hot, no barriers) ----
    const float4* qa4 = (const float4*)(qc + (size_t)(b*256 + q0)*128);
    const float4* qb4 = qa4 + 32;
    const float4* wv4 = (const float4*)wv;
    const float* p0 = kct + ((size_t)(b*16 + w))*128*64 + lane;  // span0 chunk w
    const float* p1 = p0 + 8*128*64;                             // span1 chunk w+8

    bool act0 = (w*64 < vl);
    bool act1 = (512 + w*64 < vl);
    float a00=0.f, a01=0.f, a10=0.f, a11=0.f;   // a[q][span]

    if (act1) {
#pragma unroll 2
        for (int hb = 0; hb < 32; ++hb) {
            float4 qa = qa4[hb], qb = qb4[hb], wvv = wv4[hb];   // s_load (uniform)
            float k0a = p0[0], k0b = p0[64], k0c = p0[128], k0d = p0[192];
            float k1a = p1[0], k1b = p1[64], k1c = p1[128], k1d = p1[192];
            p0 += 256; p1 += 256;
            a00 = fmaf(wvv.x, sig2(qa.x + k0a), a00);
            a10 = fmaf(wvv.x, sig2(qb.x + k0a), a10);
            a01 = fmaf(wvv.x, sig2(qa.x + k1a), a01);
            a11 = fmaf(wvv.x, sig2(qb.x + k1a), a11);
            a00 = fmaf(wvv.y, sig2(qa.y + k0b), a00);
            a10 = fmaf(wvv.y, sig2(qb.y + k0b), a10);
            a01 = fmaf(wvv.y, sig2(qa.y + k1b), a01);
            a11 = fmaf(wvv.y, sig2(qb.y + k1b), a11);
            a00 = fmaf(wvv.z, sig2(qa.z + k0c), a00);
            a10 = fmaf(wvv.z, sig2(qb.z + k0c), a10);
            a01 = fmaf(wvv.z, sig2(qa.z + k1c), a01);
            a11 = fmaf(wvv.z, sig2(qb.z + k1c), a11);
            a00 = fmaf(wvv.w, sig2(qa.w + k0d), a00);
            a10 = fmaf(wvv.w, sig2(qb.w + k0d), a10);
            a01 = fmaf(wvv.w, sig2(qa.w + k1d), a01);
            a11 = fmaf(wvv.w, sig2(qb.w + k1d), a11);
        }
    } else if (act0) {
#pragma unroll 2
        for (int hb = 0; hb < 32; ++hb) {
            float4 qa = qa4[hb], qb = qb4[hb], wvv = wv4[hb];
            float k0a = p0[0], k0b = p0[64], k0c = p0[128], k0d = p0[192];
            p0 += 256;
            a00 = fmaf(wvv.x, sig2(qa.x + k0a), a00);
            a10 = fmaf(wvv.x, sig2(qb.x + k0a), a10);
            a00 = fmaf(wvv.y, sig2(qa.y + k0b), a00);
            a10 = fmaf(wvv.y, sig2(qb.y + k0b), a10);
            a00 = fmaf(wvv.z, sig2(qa.z + k0c), a00);
            a10 = fmaf(wvv.z, sig2(qb.z + k0c), a10);
            a00 = fmaf(wvv.w, sig2(qa.w + k0d), a00);
            a10 = fmaf(wvv.w, sig2(qb.w + k0d), a10);
        }
    }

    // ---- mask + softmax (shuffle + LDS two-level) ----
    float s00 = (kvl       < vl) ? -2.f*a00 : -1e6f;
    float s10 = (kvl       < vl) ? -2.f*a10 : -1e6f;
    float s01 = (kvl + 512 < vl) ? -2.f*a01 : -1e6f;
    float s11 = (kvl + 512 < vl) ? -2.f*a11 : -1e6f;

    float m0 = fmaxf(s00, s01), m1 = fmaxf(s10, s11);
#pragma unroll
    for (int off = 32; off; off >>= 1) {
        m0 = fmaxf(m0, __shfl_xor(m0, off));
        m1 = fmaxf(m1, __shfl_xor(m1, off));
    }
    if (lane == 0) { red_m[w][0] = m0; red_m[w][1] = m1; }
    __syncthreads();
    m0 = red_m[0][0]; m1 = red_m[0][1];
#pragma unroll
    for (int ww = 1; ww < 8; ++ww) {
        m0 = fmaxf(m0, red_m[ww][0]);
        m1 = fmaxf(m1, red_m[ww][1]);
    }

    float e00 = __builtin_amdgcn_exp2f((s00 - m0) * LOG2E);
    float e10 = __builtin_amdgcn_exp2f((s10 - m1) * LOG2E);
    float e01 = __builtin_amdgcn_exp2f((s01 - m0) * LOG2E);
    float e11 = __builtin_amdgcn_exp2f((s11 - m1) * LOG2E);
    e2_s[kvl]       = make_float2(e00, e10);
    e2_s[kvl + 512] = make_float2(e01, e11);
    float l0 = e00 + e01, l1 = e10 + e11;
#pragma unroll
    for (int off = 32; off; off >>= 1) {
        l0 += __shfl_xor(l0, off);
        l1 += __shfl_xor(l1, off);
    }
    if (lane == 0) { red_s[w][0] = l0; red_s[w][1] = l1; }
    __syncthreads();
    float sum0 = red_s[0][0], sum1 = red_s[0][1];
#pragma unroll
    for (int ww = 1; ww < 8; ++ww) { sum0 += red_s[ww][0]; sum1 += red_s[ww][1]; }
    float inv0 = 1.0f / sum0, inv1 = 1.0f / sum1;

    // ---- PV: wave w takes kv = w, w+8, ... (< vl only; e==0 beyond) ----
    int kv_end = (vl == 0) ? 1024 : vl;
    float4 ac0 = {0,0,0,0}, ac1 = {0,0,0,0};
    const float4* V4 = (const float4*)values + (size_t)b*1024*64 + lane;
#pragma unroll 2
    for (int kv = w; kv < kv_end; kv += 8) {
        float4 vv = V4[(size_t)kv*64];          // coalesced 1KB/wave
        float2 ee = e2_s[kv];                   // broadcast
        ac0.x = fmaf(ee.x, vv.x, ac0.x); ac0.y = fmaf(ee.x, vv.y, ac0.y);
        ac0.z = fmaf(ee.x, vv.z, ac0.z); ac0.w = fmaf(ee.x, vv.w, ac0.w);
        ac1.x = fmaf(ee.y, vv.x, ac1.x); ac1.y = fmaf(ee.y, vv.y, ac1.y);
        ac1.z = fmaf(ee.y, vv.z, ac1.z); ac1.w = fmaf(ee.y, vv.w, ac1.w);
    }
    po[w][0][lane] = ac0;
    po[w][1][lane] = ac1;
    __syncthreads();

    int qq = tid >> 8, col = tid & 255;
    const float* pp = (const float*)po;         // [w][q][256] floats
    float r = 0.f;
#pragma unroll
    for (int ww = 0; ww < 8; ++ww) r += pp[(ww*2 + qq)*256 + col];
    float inv = qq ? inv1 : inv0;
    out[((size_t)(b*256 + q0 + qq))*256 + col] = r * inv;
}

extern "C" void kernel_launch(void* const* d_in, const int* in_sizes, int n_in,
                              void* d_out, int out_size, void* d_ws, size_t ws_size,
                              hipStream_t stream)
{
    const float* queries = (const float*)d_in[0];   // [4,256,128]
    const float* keys    = (const float*)d_in[1];   // [4,1024,128]
    const float* values  = (const float*)d_in[2];   // [4,1024,256]
    const int*   vlens   = (const int*)d_in[3];     // [4]
    const float* Wq      = (const float*)d_in[4];   // [128,128]
    const float* Wk      = (const float*)d_in[5];   // [128,128]
    const float* wv      = (const float*)d_in[6];   // [128]
    float* out = (float*)d_out;                     // [4,256,256]

    float* qc  = (float*)d_ws;                      // 4*256*128 floats
    float* kct = qc + 4*256*128;                    // 4*16*128*64 floats (tiled transpose)

    proj_kernel<<<1280, 256, 0, stream>>>(queries, keys, Wq, Wk, qc, kct);
    attn_kernel<<<dim3(128, 4), 512, 0, stream>>>(qc, kct, values, vlens, wv, out);
}